// Round 1
// baseline (583.650 us; speedup 1.0000x reference)
//
#include <hip/hip_runtime.h>
#include <stdint.h>
#include <stddef.h>

#define F_FIELDS 39
#define VOCAB    200000
#define EMB      16
#define BATCH    16384
#define MBLK     64      // samples per block (4 m-tiles x 16)
#define NOUT     64      // 32 first_order + 32 s
#define KPAD     640     // 624 padded to 640
#define NCHUNK   10
#define CSTR     68      // C_sh row stride (f32)

typedef __attribute__((ext_vector_type(8))) short bf16x8;
typedef __attribute__((ext_vector_type(4))) float f32x4;

__device__ __forceinline__ unsigned short f2bf(float x) {
  union { float f; unsigned int u; } a; a.f = x;
  unsigned int r = (a.u + 0x7fffu + ((a.u >> 16) & 1u)) >> 16;
  return (unsigned short)r;
}

// Fragment-major Wt: element (n,k) -> Wt[(k>>3)*512 + n*8 + (k&7)]
// so a lane's 8-elem B-fragment (fixed n, k0=c*64+kk*32+quad*8) is 16B contiguous,
// and lanes with consecutive n are 16B-stride coalesced.
__global__ void prep_w(const float* __restrict__ W1, const float* __restrict__ Wi,
                       unsigned short* __restrict__ Wt) {
  int i = blockIdx.x * 256 + threadIdx.x;
  if (i >= NOUT * KPAD) return;
  int n = i / KPAD, k = i % KPAD;
  float v = 0.0f;
  if (k < F_FIELDS * EMB) v = (n < 32) ? W1[n * 624 + k] : Wi[(n - 32) * 624 + k];
  Wt[(k >> 3) * 512 + n * 8 + (k & 7)] = f2bf(v);
}

// ---- pipeline macros (fully unrolled loop -> all indices compile-time) ----

// A: lane (l15,quad) gathers its own MFMA A-fragment: 8 floats of
// field f = c*4 + kk*2 + (quad>>1), elems (quad&1)*8 .. +8, row = its sample.
#define PNN_ISSUE_A(c) do {                                                   \
  _Pragma("unroll")                                                           \
  for (int h_ = 0; h_ < 2; ++h_) {                                           \
    int f_ = (c) * 4 + h_ * 2 + q2;                                          \
    if (f_ >= F_FIELDS) f_ = 0; /* xv already zeroed for invalid */          \
    const float* p_ = tb + (unsigned)((f_ * VOCAB + idxv[(c)][h_]) * EMB);   \
    va[(c) % 3][h_][0] = *(const float4*)p_;                                 \
    va[(c) % 3][h_][1] = *(const float4*)(p_ + 4);                           \
  }                                                                           \
} while (0)

// B: coalesced 16B fragment loads from fragment-major Wt (L2-resident).
#define PNN_ISSUE_B(c) do {                                                   \
  _Pragma("unroll")                                                           \
  for (int kk_ = 0; kk_ < 2; ++kk_) {                                        \
    const unsigned short* pc_ = pB + ((c) * 2 + kk_) * 2048;                 \
    vb[(c) % 2][kk_][0] = *(const bf16x8*)pc_;                               \
    vb[(c) % 2][kk_][1] = *(const bf16x8*)(pc_ + 128);                       \
  }                                                                           \
} while (0)

// convert in regs (hi = truncation, lo = rne residual) then 8 MFMA
#define PNN_COMPUTE(c) do {                                                   \
  _Pragma("unroll")                                                           \
  for (int kk_ = 0; kk_ < 2; ++kk_) {                                        \
    const float xv_ = xvv[(c)][kk_];                                         \
    const float4 v0_ = va[(c) % 3][kk_][0];                                  \
    const float4 v1_ = va[(c) % 3][kk_][1];                                  \
    const float vals_[8] = { v0_.x * xv_, v0_.y * xv_, v0_.z * xv_, v0_.w * xv_, \
                             v1_.x * xv_, v1_.y * xv_, v1_.z * xv_, v1_.w * xv_ }; \
    bf16x8 ah_, al_;                                                          \
    _Pragma("unroll")                                                         \
    for (int j_ = 0; j_ < 8; ++j_) {                                         \
      union { float f; unsigned int u; } a_; a_.f = vals_[j_];               \
      union { unsigned int u; float f; } b_; b_.u = a_.u & 0xffff0000u;      \
      ah_[j_] = (short)(a_.u >> 16);                                         \
      al_[j_] = (short)f2bf(vals_[j_] - b_.f);                               \
    }                                                                         \
    const bf16x8 b0_ = vb[(c) % 2][kk_][0];                                  \
    const bf16x8 b1_ = vb[(c) % 2][kk_][1];                                  \
    acc0 = __builtin_amdgcn_mfma_f32_16x16x32_bf16(ah_, b0_, acc0, 0, 0, 0); \
    acc1 = __builtin_amdgcn_mfma_f32_16x16x32_bf16(ah_, b1_, acc1, 0, 0, 0); \
    acc0 = __builtin_amdgcn_mfma_f32_16x16x32_bf16(al_, b0_, acc0, 0, 0, 0); \
    acc1 = __builtin_amdgcn_mfma_f32_16x16x32_bf16(al_, b1_, acc1, 0, 0, 0); \
  }                                                                           \
} while (0)

__global__ __launch_bounds__(512, 2) void pnn_main(
    const int* __restrict__ Xi, const float* __restrict__ Xv,
    const float* __restrict__ tables, const unsigned short* __restrict__ Wt,
    const float* __restrict__ lin1_w, const float* __restrict__ lin1_b,
    const float* __restrict__ lin2_w, const float* __restrict__ lin2_b,
    const float* __restrict__ last_w, const float* __restrict__ last_b,
    float* __restrict__ out)
{
  const int t    = threadIdx.x;
  const int wave = t >> 6, lane = t & 63;
  const int l15  = lane & 15, quad = lane >> 4;
  const int q2   = quad >> 1, qh = quad & 1;
  const int m_tile = wave & 3, n_half = wave >> 2;

  __shared__ float C_sh[MBLK * CSTR];    // 17.0 KB
  __shared__ float X1_sh[MBLK * 36];     //  9.0 KB
  __shared__ float W_lds[2145];          //  8.4 KB

  // ---- stage MLP weights (first read is after the post-GEMM barriers) ----
  for (int i = t; i < 1024; i += 512) {
    W_lds[i]        = lin1_w[i];
    W_lds[1024 + i] = lin2_w[i];
  }
  if (t < 32) {
    W_lds[2048 + t] = lin1_b[t];
    W_lds[2080 + t] = lin2_b[t];
    W_lds[2112 + t] = last_w[t];
  }
  if (t == 0) W_lds[2144] = last_b[0];

  const int sample = blockIdx.x * MBLK + m_tile * 16 + l15;

  // ---- preload all indices / value-scales for this lane's fragments ----
  int   idxv[NCHUNK][2];
  float xvv[NCHUNK][2];
#pragma unroll
  for (int c = 0; c < NCHUNK; ++c) {
#pragma unroll
    for (int h = 0; h < 2; ++h) {
      int f = c * 4 + h * 2 + q2;
      bool valid = (f < F_FIELDS);
      int g = sample * F_FIELDS + (valid ? f : 0);
      idxv[c][h] = valid ? Xi[g] : 0;
      xvv[c][h]  = valid ? Xv[g] : 0.0f;
    }
  }

  const float* tb = tables + qh * 8;                     // lane's 32B half of a row
  const unsigned short* pB = Wt + quad * 512 + (n_half * 32 + l15) * 8;

  float4 va[3][2][2];        // A prefetch ring: 3 chunks x 2 kk x 32B
  bf16x8 vb[2][2][2];        // B prefetch ring: 2 chunks x 2 kk x {n, n+16}
  f32x4 acc0 = {0.f, 0.f, 0.f, 0.f};
  f32x4 acc1 = {0.f, 0.f, 0.f, 0.f};

  // ---- barrier-free, register-pipelined K loop (A 2 ahead, B 1 ahead) ----
  PNN_ISSUE_A(0);
  PNN_ISSUE_A(1);
  PNN_ISSUE_B(0);
#pragma unroll
  for (int c = 0; c < NCHUNK; ++c) {
    if (c + 2 < NCHUNK) PNN_ISSUE_A(c + 2);
    if (c + 1 < NCHUNK) PNN_ISSUE_B(c + 1);
    PNN_COMPUTE(c);
  }

  // ---- C -> LDS (D layout: row = quad*4+reg, col = lane&15) ----
  {
    int row_base = m_tile * 16 + quad * 4;
    int col0 = n_half * 32 + l15;
#pragma unroll
    for (int r = 0; r < 4; ++r) {
      C_sh[(row_base + r) * CSTR + col0]      = acc0[r];
      C_sh[(row_base + r) * CSTR + col0 + 16] = acc1[r];
    }
  }
  __syncthreads();

  // ---- x = first_order + s*s (in-place into cols 0..31) ----
  {
    int m = t >> 3, j0 = (t & 7) * 4;
#pragma unroll
    for (int j = 0; j < 4; ++j) {
      float fo = C_sh[m * CSTR + j0 + j];
      float s  = C_sh[m * CSTR + 32 + j0 + j];
      C_sh[m * CSTR + j0 + j] = fo + s * s;
    }
  }
  __syncthreads();

  // ---- layer 1: x1 = relu(x @ lin1_w.T + b1) ----
  {
    const int m = t >> 3, d0 = (t & 7) * 4;
    float a0 = W_lds[2048 + d0 + 0];
    float a1 = W_lds[2048 + d0 + 1];
    float a2 = W_lds[2048 + d0 + 2];
    float a3 = W_lds[2048 + d0 + 3];
#pragma unroll
    for (int j = 0; j < 32; ++j) {
      float xj = C_sh[m * CSTR + j];
      a0 = fmaf(W_lds[(d0 + 0) * 32 + j], xj, a0);
      a1 = fmaf(W_lds[(d0 + 1) * 32 + j], xj, a1);
      a2 = fmaf(W_lds[(d0 + 2) * 32 + j], xj, a2);
      a3 = fmaf(W_lds[(d0 + 3) * 32 + j], xj, a3);
    }
    X1_sh[m * 36 + d0 + 0] = fmaxf(a0, 0.0f);
    X1_sh[m * 36 + d0 + 1] = fmaxf(a1, 0.0f);
    X1_sh[m * 36 + d0 + 2] = fmaxf(a2, 0.0f);
    X1_sh[m * 36 + d0 + 3] = fmaxf(a3, 0.0f);
  }
  __syncthreads();

  // ---- layer 2: x2 = relu(x1 @ lin2_w.T + b2) -> C_sh cols 32..63 ----
  {
    const int m = t >> 3, d0 = (t & 7) * 4;
    float a0 = W_lds[2080 + d0 + 0];
    float a1 = W_lds[2080 + d0 + 1];
    float a2 = W_lds[2080 + d0 + 2];
    float a3 = W_lds[2080 + d0 + 3];
#pragma unroll
    for (int j = 0; j < 32; ++j) {
      float xj = X1_sh[m * 36 + j];
      a0 = fmaf(W_lds[1024 + (d0 + 0) * 32 + j], xj, a0);
      a1 = fmaf(W_lds[1024 + (d0 + 1) * 32 + j], xj, a1);
      a2 = fmaf(W_lds[1024 + (d0 + 2) * 32 + j], xj, a2);
      a3 = fmaf(W_lds[1024 + (d0 + 3) * 32 + j], xj, a3);
    }
    C_sh[m * CSTR + 32 + d0 + 0] = fmaxf(a0, 0.0f);
    C_sh[m * CSTR + 32 + d0 + 1] = fmaxf(a1, 0.0f);
    C_sh[m * CSTR + 32 + d0 + 2] = fmaxf(a2, 0.0f);
    C_sh[m * CSTR + 32 + d0 + 3] = fmaxf(a3, 0.0f);
  }
  __syncthreads();

  // ---- last: out[m] = x2 @ last_w.T + last_b ----
  if (t < MBLK) {
    float s = W_lds[2144];
#pragma unroll
    for (int j = 0; j < 32; ++j)
      s = fmaf(W_lds[2112 + j], C_sh[t * CSTR + 32 + j], s);
    out[blockIdx.x * MBLK + t] = s;
  }
}

extern "C" void kernel_launch(void* const* d_in, const int* in_sizes, int n_in,
                              void* d_out, int out_size, void* d_ws, size_t ws_size,
                              hipStream_t stream) {
  (void)in_sizes; (void)n_in; (void)out_size; (void)ws_size;
  const int*   Xi     = (const int*)d_in[0];
  const float* Xv     = (const float*)d_in[1];
  const float* tables = (const float*)d_in[2];
  const float* W1     = (const float*)d_in[3];
  const float* Wi     = (const float*)d_in[4];
  const float* l1w    = (const float*)d_in[5];
  const float* l1b    = (const float*)d_in[6];
  const float* l2w    = (const float*)d_in[7];
  const float* l2b    = (const float*)d_in[8];
  const float* lw     = (const float*)d_in[9];
  const float* lb     = (const float*)d_in[10];
  float* out = (float*)d_out;

  unsigned short* Wt = (unsigned short*)d_ws;  // 64*640 bf16 = 80 KB

  prep_w<<<dim3((NOUT * KPAD + 255) / 256), dim3(256), 0, stream>>>(W1, Wi, Wt);
  pnn_main<<<dim3(BATCH / MBLK), dim3(512), 0, stream>>>(
      Xi, Xv, tables, Wt, l1w, l1b, l2w, l2b, lw, lb, out);
}